// Round 2
// baseline (885.757 us; speedup 1.0000x reference)
//
#include <hip/hip_runtime.h>

#define N_NODES 50000
#define N_EDGES 800000
#define CH 128
#define N_GRAPHS 128
#define N_LAYERS 3
#define OUT_CH 16
#define BN_EPS 1e-5f

// ---------------- CSR build ----------------

__global__ void hist_kernel(const int* __restrict__ dst, int* __restrict__ deg) {
    int i = blockIdx.x * blockDim.x + threadIdx.x;
    if (i < N_EDGES) atomicAdd(&deg[dst[i]], 1);
}

__global__ __launch_bounds__(1024) void scan_kernel(const int* __restrict__ deg,
                                                    int* __restrict__ rowptr) {
    __shared__ int sdata[1024];
    __shared__ int s_carry;
    int t = threadIdx.x;
    if (t == 0) s_carry = 0;
    __syncthreads();
    for (int base = 0; base < N_NODES; base += 1024) {
        int v = (base + t < N_NODES) ? deg[base + t] : 0;
        sdata[t] = v;
        __syncthreads();
        #pragma unroll
        for (int off = 1; off < 1024; off <<= 1) {
            int y = (t >= off) ? sdata[t - off] : 0;
            __syncthreads();
            sdata[t] += y;
            __syncthreads();
        }
        if (base + t < N_NODES) rowptr[base + t] = s_carry + sdata[t] - v;
        int tot = sdata[1023];
        __syncthreads();
        if (t == 0) s_carry += tot;
        __syncthreads();
    }
    if (t == 0) rowptr[N_NODES] = s_carry;  // == N_EDGES
}

__global__ void copy_int_kernel(const int* __restrict__ a, int* __restrict__ b, int n) {
    int i = blockIdx.x * blockDim.x + threadIdx.x;
    if (i < n) b[i] = a[i];
}

__global__ void fill_kernel(const int* __restrict__ src, const int* __restrict__ dst,
                            int* __restrict__ cursor, int* __restrict__ esrc) {
    int i = blockIdx.x * blockDim.x + threadIdx.x;
    if (i < N_EDGES) {
        int d = dst[i];
        int p = atomicAdd(&cursor[d], 1);
        esrc[p] = src[i];
    }
}

// graph start offsets from sorted batch vector
__global__ void starts_kernel(const int* __restrict__ batch, int* __restrict__ starts) {
    int i = blockIdx.x * blockDim.x + threadIdx.x;
    if (i >= N_NODES) return;
    int b = batch[i];
    if (i == 0) {
        for (int g = 0; g <= b; ++g) starts[g] = 0;
    } else {
        int pb = batch[i - 1];
        for (int g = pb + 1; g <= b; ++g) starts[g] = i;
    }
    if (i == N_NODES - 1) {
        for (int g = b + 1; g <= N_GRAPHS; ++g) starts[g] = N_NODES;
    }
}

// ---------------- aggregation: z[v] = h[v] + sum_{e: dst=v} h[src_e] ----------------
// one wave per node; lane = float2 channel pair; 4x edge unroll for latency hiding
__global__ __launch_bounds__(256) void agg_kernel(const float* __restrict__ h,
                                                  const int* __restrict__ rowptr,
                                                  const int* __restrict__ esrc,
                                                  float* __restrict__ z) {
    int wid = (blockIdx.x * 256 + threadIdx.x) >> 6;
    int lane = threadIdx.x & 63;
    if (wid >= N_NODES) return;
    const float2* __restrict__ h2 = (const float2*)h;
    float2 acc = h2[wid * 64 + lane];
    int beg = rowptr[wid], end = rowptr[wid + 1];
    int e = beg;
    for (; e + 4 <= end; e += 4) {
        int s0 = esrc[e], s1 = esrc[e + 1], s2 = esrc[e + 2], s3 = esrc[e + 3];
        float2 v0 = h2[s0 * 64 + lane];
        float2 v1 = h2[s1 * 64 + lane];
        float2 v2 = h2[s2 * 64 + lane];
        float2 v3 = h2[s3 * 64 + lane];
        acc.x += v0.x + v1.x + v2.x + v3.x;
        acc.y += v0.y + v1.y + v2.y + v3.y;
    }
    for (; e < end; ++e) {
        int s = esrc[e];
        float2 v = h2[s * 64 + lane];
        acc.x += v.x; acc.y += v.y;
    }
    ((float2*)z)[wid * 64 + lane] = acc;
}

// ---------------- fp32 GEMM: Out = epilogue(A[M,128] @ W[128,128] + bias) ----------------
// mode 0: relu(acc + b);  mode 1: relu((acc + b - mean)*gamma*rsqrt(var+eps) + beta)
// block: 256 thr (tx=16 col-groups, ty=16 row-groups); tile 64 rows x 128 cols; 4x8 per thread
__global__ __launch_bounds__(256) void gemm_kernel(
    const float* __restrict__ A, const float* __restrict__ W,
    const float* __restrict__ bias,
    const float* __restrict__ mean_, const float* __restrict__ var_,
    const float* __restrict__ gamma_, const float* __restrict__ beta_,
    float* __restrict__ Out, int mode)
{
    __shared__ float Ws[CH][CH];     // [k][c]  64 KB
    __shared__ float As[32][68];     // [k][row] padded

    int t = threadIdx.x;
    int tx = t & 15, ty = t >> 4;
    int block_row = blockIdx.x * 64;

    {   // cooperative W load (flat float4)
        const float4* Wv = (const float4*)W;
        float4* Wsv = (float4*)&Ws[0][0];
        for (int i = t; i < (CH * CH) / 4; i += 256) Wsv[i] = Wv[i];
    }

    float acc[4][8];
    #pragma unroll
    for (int r = 0; r < 4; ++r)
        #pragma unroll
        for (int c = 0; c < 8; ++c) acc[r][c] = 0.f;

    for (int k0 = 0; k0 < CH; k0 += 32) {
        // stage A chunk transposed: 64 rows x 32 k
        int lr = t >> 2;           // row 0..63
        int lk = (t & 3) * 8;      // k offset 0,8,16,24
        int grow = block_row + lr;
        float va[8];
        if (grow < N_NODES) {
            const float4* ap = (const float4*)&A[(size_t)grow * CH + k0 + lk];
            float4 p0 = ap[0], p1 = ap[1];
            va[0] = p0.x; va[1] = p0.y; va[2] = p0.z; va[3] = p0.w;
            va[4] = p1.x; va[5] = p1.y; va[6] = p1.z; va[7] = p1.w;
        } else {
            #pragma unroll
            for (int j = 0; j < 8; ++j) va[j] = 0.f;
        }
        __syncthreads();   // covers Ws first use + As reuse hazard
        #pragma unroll
        for (int j = 0; j < 8; ++j) As[lk + j][lr] = va[j];
        __syncthreads();

        #pragma unroll
        for (int kk = 0; kk < 32; ++kk) {
            float a[4], w[8];
            int k = k0 + kk;
            #pragma unroll
            for (int r = 0; r < 4; ++r) a[r] = As[kk][ty * 4 + r];
            #pragma unroll
            for (int j = 0; j < 4; ++j) w[j] = Ws[k][tx * 4 + j];
            #pragma unroll
            for (int j = 0; j < 4; ++j) w[4 + j] = Ws[k][64 + tx * 4 + j];
            #pragma unroll
            for (int r = 0; r < 4; ++r)
                #pragma unroll
                for (int c = 0; c < 8; ++c) acc[r][c] += a[r] * w[c];
        }
    }

    // epilogue
    #pragma unroll
    for (int r = 0; r < 4; ++r) {
        int grow = block_row + ty * 4 + r;
        if (grow >= N_NODES) continue;
        #pragma unroll
        for (int cg = 0; cg < 2; ++cg) {
            int cbase = cg * 64 + tx * 4;
            float4 v;
            float vv[4];
            #pragma unroll
            for (int j = 0; j < 4; ++j) {
                int c = cbase + j;
                float z = acc[r][cg * 4 + j] + bias[c];
                if (mode == 1) {
                    float inv = gamma_[c] * rsqrtf(var_[c] + BN_EPS);
                    z = (z - mean_[c]) * inv + beta_[c];
                }
                vv[j] = fmaxf(z, 0.f);
            }
            v.x = vv[0]; v.y = vv[1]; v.z = vv[2]; v.w = vv[3];
            *(float4*)&Out[(size_t)grow * CH + cbase] = v;
        }
    }
}

// ---------------- pooling + classifier ----------------

__global__ __launch_bounds__(128) void pool_kernel(const float* __restrict__ h,
                                                   const int* __restrict__ starts,
                                                   float* __restrict__ pooled) {
    int g = blockIdx.x;
    int c = threadIdx.x;
    float s = 0.f;
    int beg = starts[g], end = starts[g + 1];
    for (int n = beg; n < end; ++n) s += h[(size_t)n * CH + c];
    pooled[g * CH + c] = s;
}

__global__ __launch_bounds__(256) void cls_kernel(const float* __restrict__ pooled,
                                                  const float* __restrict__ Wc,
                                                  const float* __restrict__ bc,
                                                  float* __restrict__ out) {
    int i = blockIdx.x * blockDim.x + threadIdx.x;
    if (i >= N_GRAPHS * OUT_CH) return;
    int g = i / OUT_CH, o = i % OUT_CH;
    float s = bc[o];
    for (int k = 0; k < CH; ++k) s += pooled[g * CH + k] * Wc[k * OUT_CH + o];
    out[i] = s;
}

// ---------------- launch ----------------

extern "C" void kernel_launch(void* const* d_in, const int* in_sizes, int n_in,
                              void* d_out, int out_size, void* d_ws, size_t ws_size,
                              hipStream_t stream) {
    const float* x     = (const float*)d_in[0];
    const int*   eidx  = (const int*)d_in[1];   // int32! (JAX x64 disabled)
    const int*   batch = (const int*)d_in[2];
    const float* W1    = (const float*)d_in[3];
    const float* b1    = (const float*)d_in[4];
    const float* W2    = (const float*)d_in[5];
    const float* b2    = (const float*)d_in[6];
    const float* gamma = (const float*)d_in[7];
    const float* beta  = (const float*)d_in[8];
    const float* mean  = (const float*)d_in[9];
    const float* var   = (const float*)d_in[10];
    const float* Wc    = (const float*)d_in[11];
    const float* bc    = (const float*)d_in[12];
    float* out = (float*)d_out;

    const int* src = eidx;
    const int* dst = eidx + N_EDGES;

    // workspace layout (256B aligned blocks) — ~55 MB total
    char* w = (char*)d_ws;
    size_t off = 0;
    auto alloc = [&](size_t bytes) { void* p = w + off; off += (bytes + 255) & ~(size_t)255; return p; };
    int*   deg    = (int*)alloc(N_NODES * 4);
    int*   rowptr = (int*)alloc((N_NODES + 1) * 4);
    int*   cursor = (int*)alloc(N_NODES * 4);
    int*   esrc   = (int*)alloc(N_EDGES * 4);
    int*   starts = (int*)alloc((N_GRAPHS + 1) * 4);
    float* bufA   = (float*)alloc((size_t)N_NODES * CH * 4);
    float* bufB   = (float*)alloc((size_t)N_NODES * CH * 4);
    float* pooled = (float*)alloc(N_GRAPHS * CH * 4);
    (void)ws_size; (void)n_in; (void)in_sizes; (void)out_size;

    // CSR build (reused by all 3 layers)
    hipMemsetAsync(deg, 0, N_NODES * 4, stream);
    hist_kernel<<<(N_EDGES + 255) / 256, 256, 0, stream>>>(dst, deg);
    scan_kernel<<<1, 1024, 0, stream>>>(deg, rowptr);
    copy_int_kernel<<<(N_NODES + 255) / 256, 256, 0, stream>>>(rowptr, cursor, N_NODES);
    fill_kernel<<<(N_EDGES + 255) / 256, 256, 0, stream>>>(src, dst, cursor, esrc);
    starts_kernel<<<(N_NODES + 255) / 256, 256, 0, stream>>>(batch, starts);

    const int agg_grid  = (N_NODES + 3) / 4;          // 1 wave/node, 4 waves/block
    const int gemm_grid = (N_NODES + 63) / 64;

    // ping-pong: agg(hin -> zagg), gemm1(zagg -> zmid), gemm2(zmid -> zagg)
    float* bufs[2] = {bufA, bufB};
    const float* hin = x;
    int cur = 0;
    for (int i = 0; i < N_LAYERS; ++i) {
        float* zagg = bufs[cur];
        float* zmid = bufs[cur ^ 1];
        agg_kernel<<<agg_grid, 256, 0, stream>>>(hin, rowptr, esrc, zagg);
        gemm_kernel<<<gemm_grid, 256, 0, stream>>>(
            zagg, W1 + (size_t)i * CH * CH, b1 + i * CH,
            nullptr, nullptr, nullptr, nullptr, zmid, 0);
        gemm_kernel<<<gemm_grid, 256, 0, stream>>>(
            zmid, W2 + (size_t)i * CH * CH, b2 + i * CH,
            mean + i * CH, var + i * CH, gamma + i * CH, beta + i * CH, zagg, 1);
        hin = zagg;
        cur ^= 1;
    }

    pool_kernel<<<N_GRAPHS, 128, 0, stream>>>((const float*)hin, starts, pooled);
    cls_kernel<<<(N_GRAPHS * OUT_CH + 255) / 256, 256, 0, stream>>>(pooled, Wc, bc, out);
}

// Round 3
// 463.274 us; speedup vs baseline: 1.9120x; 1.9120x over previous
//
#include <hip/hip_runtime.h>

#define N_NODES 50000
#define N_EDGES 800000
#define CH 128
#define N_GRAPHS 128
#define N_LAYERS 3
#define OUT_CH 16
#define BN_EPS 1e-5f
#define NCHUNK ((N_NODES + 1023) / 1024)
#define NSPLIT 8

typedef unsigned short ushort_t;
typedef __attribute__((ext_vector_type(8))) short bf16x8;
typedef __attribute__((ext_vector_type(4))) float f32x4;

// fp32 -> bf16 (RNE) without header type gymnastics
__device__ inline ushort_t f2b(float f) {
    unsigned u = __float_as_uint(f);
    unsigned r = (u + 0x7fffu + ((u >> 16) & 1u)) >> 16;
    return (ushort_t)r;
}
__device__ inline float b2f(ushort_t b) {
    return __uint_as_float((unsigned)b << 16);
}

// ---------------- fp32 -> bf16 cast of x ----------------
__global__ __launch_bounds__(256) void cast_kernel(const float4* __restrict__ x,
                                                   ushort4* __restrict__ xb, int n4) {
    int i = blockIdx.x * blockDim.x + threadIdx.x;
    if (i >= n4) return;
    float4 v = x[i];
    ushort4 o;
    o.x = f2b(v.x); o.y = f2b(v.y); o.z = f2b(v.z); o.w = f2b(v.w);
    xb[i] = o;
}

// ---------------- CSR build ----------------
__global__ void hist_kernel(const int* __restrict__ dst, int* __restrict__ deg) {
    int i = blockIdx.x * blockDim.x + threadIdx.x;
    if (i < N_EDGES) atomicAdd(&deg[dst[i]], 1);
}

__global__ __launch_bounds__(1024) void scan1_kernel(const int* __restrict__ deg,
                                                     int* __restrict__ rowptr,
                                                     int* __restrict__ bsum) {
    __shared__ int sdata[1024];
    int t = threadIdx.x, base = blockIdx.x * 1024;
    int v = (base + t < N_NODES) ? deg[base + t] : 0;
    sdata[t] = v;
    __syncthreads();
    #pragma unroll
    for (int off = 1; off < 1024; off <<= 1) {
        int y = (t >= off) ? sdata[t - off] : 0;
        __syncthreads();
        sdata[t] += y;
        __syncthreads();
    }
    if (base + t < N_NODES) rowptr[base + t] = sdata[t] - v;   // local exclusive
    if (t == 1023) bsum[blockIdx.x] = sdata[1023];
}

__global__ void scan2_kernel(const int* __restrict__ bsum, int* __restrict__ boff) {
    int lane = threadIdx.x;  // single wave of 64
    int v = (lane < NCHUNK) ? bsum[lane] : 0;
    int orig = v;
    #pragma unroll
    for (int off = 1; off < 64; off <<= 1) {
        int tv = __shfl_up(v, off);
        if (lane >= off) v += tv;
    }
    if (lane < NCHUNK) boff[lane] = v - orig;
}

__global__ __launch_bounds__(1024) void scan3_kernel(int* __restrict__ rowptr,
                                                     const int* __restrict__ boff,
                                                     int* __restrict__ cursor) {
    int i = blockIdx.x * 1024 + threadIdx.x;
    if (i < N_NODES) {
        int r = rowptr[i] + boff[blockIdx.x];
        rowptr[i] = r;
        cursor[i] = r;
    }
    if (i == 0) rowptr[N_NODES] = N_EDGES;
}

__global__ void fill_kernel(const int* __restrict__ src, const int* __restrict__ dst,
                            int* __restrict__ cursor, int* __restrict__ esrc) {
    int i = blockIdx.x * blockDim.x + threadIdx.x;
    if (i < N_EDGES) {
        int p = atomicAdd(&cursor[dst[i]], 1);
        esrc[p] = src[i];
    }
}

__global__ void starts_kernel(const int* __restrict__ batch, int* __restrict__ starts) {
    int i = blockIdx.x * blockDim.x + threadIdx.x;
    if (i >= N_NODES) return;
    int b = batch[i];
    if (i == 0) {
        for (int g = 0; g <= b; ++g) starts[g] = 0;
    } else {
        int pb = batch[i - 1];
        for (int g = pb + 1; g <= b; ++g) starts[g] = i;
    }
    if (i == N_NODES - 1) {
        for (int g = b + 1; g <= N_GRAPHS; ++g) starts[g] = N_NODES;
    }
}

// ---------------- weight / epilogue prep ----------------
// Wt layout: [mat][n][k] bf16, mats 0..2 = W1 layers, 3..5 = W2 layers
__global__ __launch_bounds__(256) void wprep_kernel(const float* __restrict__ W1,
                                                    const float* __restrict__ W2,
                                                    ushort_t* __restrict__ Wt) {
    int i = blockIdx.x * blockDim.x + threadIdx.x;
    if (i >= 6 * CH * CH) return;
    int mat = i / (CH * CH), rem = i % (CH * CH);
    int n = rem / CH, k = rem % CH;
    const float* Wsrc = (mat < 3) ? (W1 + (size_t)mat * CH * CH)
                                  : (W2 + (size_t)(mat - 3) * CH * CH);
    Wt[i] = f2b(Wsrc[k * CH + n]);
}

// scale/shift per gemm: mats 0..2 (W1): y = relu(acc + b1)
//                       mats 3..5 (W2): y = relu(acc*inv + (b2-mean)*inv + beta)
__global__ void eprep_kernel(const float* __restrict__ b1, const float* __restrict__ b2,
                             const float* __restrict__ gamma, const float* __restrict__ beta,
                             const float* __restrict__ mean, const float* __restrict__ var,
                             float* __restrict__ scale, float* __restrict__ shift) {
    int i = blockIdx.x * blockDim.x + threadIdx.x;
    if (i >= 6 * CH) return;
    int mat = i / CH, c = i % CH;
    if (mat < 3) {
        scale[i] = 1.f;
        shift[i] = b1[mat * CH + c];
    } else {
        int l = mat - 3;
        float inv = gamma[l * CH + c] * rsqrtf(var[l * CH + c] + BN_EPS);
        scale[i] = inv;
        shift[i] = (b2[l * CH + c] - mean[l * CH + c]) * inv + beta[l * CH + c];
    }
}

// ---------------- aggregation (bf16 in/out, fp32 accumulate) ----------------
// one wave per node; lane = 2 channels (one dword)
__global__ __launch_bounds__(256) void agg_kernel(const unsigned* __restrict__ h2,
                                                  const int* __restrict__ rowptr,
                                                  const int* __restrict__ esrc,
                                                  unsigned* __restrict__ z2) {
    int wid = (blockIdx.x * 256 + threadIdx.x) >> 6;
    int lane = threadIdx.x & 63;
    if (wid >= N_NODES) return;
    unsigned self = h2[wid * 64 + lane];
    float ax = b2f((ushort_t)(self & 0xffff));
    float ay = __uint_as_float(self & 0xffff0000u);
    int beg = rowptr[wid], end = rowptr[wid + 1];
    int e = beg;
    for (; e + 4 <= end; e += 4) {
        int s0 = esrc[e], s1 = esrc[e + 1], s2 = esrc[e + 2], s3 = esrc[e + 3];
        unsigned u0 = h2[s0 * 64 + lane];
        unsigned u1 = h2[s1 * 64 + lane];
        unsigned u2 = h2[s2 * 64 + lane];
        unsigned u3 = h2[s3 * 64 + lane];
        ax += __uint_as_float(u0 << 16) + __uint_as_float(u1 << 16)
            + __uint_as_float(u2 << 16) + __uint_as_float(u3 << 16);
        ay += __uint_as_float(u0 & 0xffff0000u) + __uint_as_float(u1 & 0xffff0000u)
            + __uint_as_float(u2 & 0xffff0000u) + __uint_as_float(u3 & 0xffff0000u);
    }
    for (; e < end; ++e) {
        unsigned u = h2[esrc[e] * 64 + lane];
        ax += __uint_as_float(u << 16);
        ay += __uint_as_float(u & 0xffff0000u);
    }
    z2[wid * 64 + lane] = ((unsigned)f2b(ay) << 16) | (unsigned)f2b(ax);
}

// ---------------- bf16 MFMA GEMM: Out = relu(A @ W * scale + shift) ----------------
// A[M,128] bf16 row-major, Wt[n][k] bf16 (W transposed), Out bf16.
// Block 256 = 4 waves; wave computes 16 rows x 128 cols; 32 mfma_f32_16x16x32_bf16.
__global__ __launch_bounds__(256) void gemm_kernel(const ushort_t* __restrict__ A,
                                                   const ushort_t* __restrict__ Wt,
                                                   const float* __restrict__ scale,
                                                   const float* __restrict__ shift,
                                                   ushort_t* __restrict__ Out) {
    int t = threadIdx.x;
    int wave = t >> 6, lane = t & 63;
    int quad = lane >> 4, l16 = lane & 15;
    int row0 = blockIdx.x * 64 + wave * 16;
    int arow = row0 + l16;
    if (arow > N_NODES - 1) arow = N_NODES - 1;   // clamp loads

    // A fragments: A[m=l16][k=quad*8+j], 4 K-steps of 32
    bf16x8 afrag[4];
    const ushort_t* abase = A + (size_t)arow * CH + quad * 8;
    #pragma unroll
    for (int ks = 0; ks < 4; ++ks)
        afrag[ks] = *(const bf16x8*)(abase + ks * 32);

    f32x4 acc[8];
    #pragma unroll
    for (int ct = 0; ct < 8; ++ct) acc[ct] = (f32x4){0.f, 0.f, 0.f, 0.f};

    #pragma unroll
    for (int ct = 0; ct < 8; ++ct) {
        const ushort_t* bbase = Wt + (size_t)(ct * 16 + l16) * CH + quad * 8;
        #pragma unroll
        for (int ks = 0; ks < 4; ++ks) {
            bf16x8 bfrag = *(const bf16x8*)(bbase + ks * 32);
            acc[ct] = __builtin_amdgcn_mfma_f32_16x16x32_bf16(afrag[ks], bfrag, acc[ct], 0, 0, 0);
        }
    }

    if (row0 >= N_NODES) return;
    // C/D layout: col = l16, row = quad*4 + reg
    #pragma unroll
    for (int ct = 0; ct < 8; ++ct) {
        int col = ct * 16 + l16;
        float sc = scale[col], sh = shift[col];
        #pragma unroll
        for (int r = 0; r < 4; ++r) {
            int row = row0 + quad * 4 + r;
            if (row < N_NODES) {
                float v = fmaxf(acc[ct][r] * sc + sh, 0.f);
                Out[(size_t)row * CH + col] = f2b(v);
            }
        }
    }
}

// ---------------- pooling (bf16 in, fp32 atomic out) + classifier ----------------
__global__ __launch_bounds__(128) void pool_kernel(const ushort_t* __restrict__ h,
                                                   const int* __restrict__ starts,
                                                   float* __restrict__ pooled) {
    int g = blockIdx.x / NSPLIT, s = blockIdx.x % NSPLIT;
    int c = threadIdx.x;
    int beg = starts[g], end = starts[g + 1];
    float sum = 0.f;
    for (int n = beg + s; n < end; n += NSPLIT)
        sum += b2f(h[(size_t)n * CH + c]);
    atomicAdd(&pooled[g * CH + c], sum);
}

__global__ __launch_bounds__(256) void cls_kernel(const float* __restrict__ pooled,
                                                  const float* __restrict__ Wc,
                                                  const float* __restrict__ bc,
                                                  float* __restrict__ out) {
    int i = blockIdx.x * blockDim.x + threadIdx.x;
    if (i >= N_GRAPHS * OUT_CH) return;
    int g = i / OUT_CH, o = i % OUT_CH;
    float s = bc[o];
    for (int k = 0; k < CH; ++k) s += pooled[g * CH + k] * Wc[k * OUT_CH + o];
    out[i] = s;
}

// ---------------- launch ----------------
extern "C" void kernel_launch(void* const* d_in, const int* in_sizes, int n_in,
                              void* d_out, int out_size, void* d_ws, size_t ws_size,
                              hipStream_t stream) {
    const float* x     = (const float*)d_in[0];
    const int*   eidx  = (const int*)d_in[1];   // int32 (JAX x64 disabled)
    const int*   batch = (const int*)d_in[2];
    const float* W1    = (const float*)d_in[3];
    const float* b1    = (const float*)d_in[4];
    const float* W2    = (const float*)d_in[5];
    const float* b2    = (const float*)d_in[6];
    const float* gamma = (const float*)d_in[7];
    const float* beta  = (const float*)d_in[8];
    const float* mean  = (const float*)d_in[9];
    const float* var   = (const float*)d_in[10];
    const float* Wc    = (const float*)d_in[11];
    const float* bc    = (const float*)d_in[12];
    float* out = (float*)d_out;

    const int* src = eidx;
    const int* dst = eidx + N_EDGES;

    char* w = (char*)d_ws;
    size_t off = 0;
    auto alloc = [&](size_t bytes) { void* p = w + off; off += (bytes + 255) & ~(size_t)255; return p; };
    int*      deg    = (int*)alloc(N_NODES * 4);
    int*      rowptr = (int*)alloc((N_NODES + 1) * 4);
    int*      cursor = (int*)alloc(N_NODES * 4);
    int*      esrc   = (int*)alloc(N_EDGES * 4);
    int*      bsum   = (int*)alloc(NCHUNK * 4);
    int*      boff   = (int*)alloc(NCHUNK * 4);
    int*      starts = (int*)alloc((N_GRAPHS + 1) * 4);
    ushort_t* B0     = (ushort_t*)alloc((size_t)N_NODES * CH * 2);
    ushort_t* B1     = (ushort_t*)alloc((size_t)N_NODES * CH * 2);
    ushort_t* B2     = (ushort_t*)alloc((size_t)N_NODES * CH * 2);
    ushort_t* Wt     = (ushort_t*)alloc((size_t)6 * CH * CH * 2);
    float*    scale  = (float*)alloc(6 * CH * 4);
    float*    shift  = (float*)alloc(6 * CH * 4);
    float*    pooled = (float*)alloc(N_GRAPHS * CH * 4);
    (void)ws_size; (void)n_in; (void)in_sizes; (void)out_size;

    // prep
    const int n4 = (N_NODES * CH) / 4;
    cast_kernel<<<(n4 + 255) / 256, 256, 0, stream>>>((const float4*)x, (ushort4*)B0, n4);
    hipMemsetAsync(deg, 0, N_NODES * 4, stream);
    hipMemsetAsync(pooled, 0, N_GRAPHS * CH * 4, stream);
    hist_kernel<<<(N_EDGES + 255) / 256, 256, 0, stream>>>(dst, deg);
    scan1_kernel<<<NCHUNK, 1024, 0, stream>>>(deg, rowptr, bsum);
    scan2_kernel<<<1, 64, 0, stream>>>(bsum, boff);
    scan3_kernel<<<NCHUNK, 1024, 0, stream>>>(rowptr, boff, cursor);
    fill_kernel<<<(N_EDGES + 255) / 256, 256, 0, stream>>>(src, dst, cursor, esrc);
    starts_kernel<<<(N_NODES + 255) / 256, 256, 0, stream>>>(batch, starts);
    wprep_kernel<<<(6 * CH * CH + 255) / 256, 256, 0, stream>>>(W1, W2, Wt);
    eprep_kernel<<<(6 * CH + 255) / 256, 256, 0, stream>>>(b1, b2, gamma, beta, mean, var, scale, shift);

    const int agg_grid  = (N_NODES + 3) / 4;
    const int gemm_grid = (N_NODES + 63) / 64;

    ushort_t* B[3] = {B0, B1, B2};
    int hin = 0;
    for (int i = 0; i < N_LAYERS; ++i) {
        int a = (hin + 1) % 3, tmp = (hin + 2) % 3;
        agg_kernel<<<agg_grid, 256, 0, stream>>>((const unsigned*)B[hin], rowptr, esrc,
                                                 (unsigned*)B[a]);
        gemm_kernel<<<gemm_grid, 256, 0, stream>>>(B[a], Wt + (size_t)i * CH * CH,
                                                   scale + i * CH, shift + i * CH, B[tmp]);
        gemm_kernel<<<gemm_grid, 256, 0, stream>>>(B[tmp], Wt + (size_t)(3 + i) * CH * CH,
                                                   scale + (3 + i) * CH, shift + (3 + i) * CH,
                                                   B[a]);
        hin = a;
    }

    pool_kernel<<<N_GRAPHS * NSPLIT, 128, 0, stream>>>(B[hin], starts, pooled);
    cls_kernel<<<(N_GRAPHS * OUT_CH + 255) / 256, 256, 0, stream>>>(pooled, Wc, bc, out);
}